// Round 2
// baseline (151.715 us; speedup 1.0000x reference)
//
#include <hip/hip_runtime.h>
#include <math.h>

#define TAU_INV 2.0f   // 1/0.5
#define EPS 1e-8f

// Native clang vector type -- __builtin_nontemporal_load requires a pointer
// to scalar/vector-of-scalar, not HIP's float4 struct.
typedef float vfloat4 __attribute__((ext_vector_type(4)));

// DPP cross-lane add on the VALU pipe (no DS/shuffle-pipe traffic).
// 0xB1=quad_perm xor1, 0x4E=quad_perm xor2, 0x141=row_half_mirror (xor7).
template<int CTRL>
__device__ __forceinline__ float dpp_add(float x) {
    int y = __builtin_amdgcn_update_dpp(0, __float_as_int(x), CTRL, 0xF, 0xF, true);
    return x + __int_as_float(y);
}

__device__ __forceinline__ vfloat4 nt_load4(const float* p) {
    // Non-temporal (no-allocate): probe caches but don't evict the harness's
    // dirty restore/poison lines. Measured prior session: 52 -> ~39 us.
    return __builtin_nontemporal_load((const vfloat4*)p);
}

// R8 MLP probe: each 8-lane slot owns a CONTIGUOUS ROW PAIR (1 KB/array).
// Per thread: 24 independent 16B nt-loads issued up front (2x the in-flight
// bytes of the 1-row version), row-B address folds into the load's 512B
// immediate offset (zero extra addr math). Both rows' serial tails
// (DPP chain + rsqrt/exp) amortize over 2 KB of traffic instead of 1 KB.
// Discriminates latency-bound (expect 39 -> ~28 us) vs BW-bound (no change).
__global__ __launch_bounds__(256) void contrast_partial(
    const float* __restrict__ xr, const float* __restrict__ xp,
    const float* __restrict__ xn, float* __restrict__ partials, int N)
{
    const int l8    = threadIdx.x & 7;       // lane within row-group
    const int rgrp  = threadIdx.x >> 3;      // 0..31 slot in block
    const int sstep = gridDim.x * 32;        // slots per grid pass

    float acc = 0.0f;
    // Single trip at nblk=1563 (loop kept only as ws-cap safety net).
    for (int slot = blockIdx.x * 32 + rgrp; 2 * slot < N; slot += sstep) {
        const int row0 = 2 * slot;
        const bool hasB = (row0 + 1) < N;    // always true for even N
        const int offB = hasB ? 128 : 0;     // fold into imm offset; dup A if odd tail
        const size_t base = (size_t)row0 * 128;
        const float* pr = xr + base;
        const float* pp = xp + base;
        const float* pn = xn + base;

        // ---- issue all 24 loads before any use (max MLP) ----
        vfloat4 rA[4], pA[4], nA[4], rB[4], pB[4], nB[4];
        #pragma unroll
        for (int j = 0; j < 4; ++j) {
            const int off = (j * 8 + l8) * 4;
            rA[j] = nt_load4(pr + off);
            pA[j] = nt_load4(pp + off);
            nA[j] = nt_load4(pn + off);
            rB[j] = nt_load4(pr + offB + off);
            pB[j] = nt_load4(pp + offB + off);
            nB[j] = nt_load4(pn + offB + off);
        }

        float aRP = 0.f, aRN = 0.f, aRR = 0.f, aPP = 0.f, aNN = 0.f;
        float bRP = 0.f, bRN = 0.f, bRR = 0.f, bPP = 0.f, bNN = 0.f;
        #pragma unroll
        for (int j = 0; j < 4; ++j) {
            const vfloat4 r = rA[j], p = pA[j], n = nA[j];
            aRP += r.x*p.x + r.y*p.y + r.z*p.z + r.w*p.w;
            aRN += r.x*n.x + r.y*n.y + r.z*n.z + r.w*n.w;
            aRR += r.x*r.x + r.y*r.y + r.z*r.z + r.w*r.w;
            aPP += p.x*p.x + p.y*p.y + p.z*p.z + p.w*p.w;
            aNN += n.x*n.x + n.y*n.y + n.z*n.z + n.w*n.w;
            const vfloat4 s = rB[j], q = pB[j], m = nB[j];
            bRP += s.x*q.x + s.y*q.y + s.z*q.z + s.w*q.w;
            bRN += s.x*m.x + s.y*m.y + s.z*m.z + s.w*m.w;
            bRR += s.x*s.x + s.y*s.y + s.z*s.z + s.w*s.w;
            bPP += q.x*q.x + q.y*q.y + q.z*q.z + q.w*q.w;
            bNN += m.x*m.x + m.y*m.y + m.z*m.z + m.w*m.w;
        }

        // 8-lane sums on the VALU pipe; all 8 lanes end with the row totals.
        aRP = dpp_add<0xB1>(aRP); aRP = dpp_add<0x4E>(aRP); aRP = dpp_add<0x141>(aRP);
        aRN = dpp_add<0xB1>(aRN); aRN = dpp_add<0x4E>(aRN); aRN = dpp_add<0x141>(aRN);
        aRR = dpp_add<0xB1>(aRR); aRR = dpp_add<0x4E>(aRR); aRR = dpp_add<0x141>(aRR);
        aPP = dpp_add<0xB1>(aPP); aPP = dpp_add<0x4E>(aPP); aPP = dpp_add<0x141>(aPP);
        aNN = dpp_add<0xB1>(aNN); aNN = dpp_add<0x4E>(aNN); aNN = dpp_add<0x141>(aNN);
        bRP = dpp_add<0xB1>(bRP); bRP = dpp_add<0x4E>(bRP); bRP = dpp_add<0x141>(bRP);
        bRN = dpp_add<0xB1>(bRN); bRN = dpp_add<0x4E>(bRN); bRN = dpp_add<0x141>(bRN);
        bRR = dpp_add<0xB1>(bRR); bRR = dpp_add<0x4E>(bRR); bRR = dpp_add<0x141>(bRR);
        bPP = dpp_add<0xB1>(bPP); bPP = dpp_add<0x4E>(bPP); bPP = dpp_add<0x141>(bPP);
        bNN = dpp_add<0xB1>(bNN); bNN = dpp_add<0x4E>(bNN); bNN = dpp_add<0x141>(bNN);

        const float invA = rsqrtf(aRR);
        const float posA = __expf(aRP * invA * rsqrtf(aPP) * TAU_INV);
        const float negA = __expf(aRN * invA * rsqrtf(aNN) * TAU_INV);
        acc += posA / (negA + EPS);

        const float invB = rsqrtf(bRR);
        const float posB = __expf(bRP * invB * rsqrtf(bPP) * TAU_INV);
        const float negB = __expf(bRN * invB * rsqrtf(bNN) * TAU_INV);
        if (hasB) acc += posB / (negB + EPS);
    }

    __shared__ float part[32];
    if (l8 == 0) part[rgrp] = acc;
    __syncthreads();
    if (threadIdx.x == 0) {
        float t = 0.f;
        #pragma unroll
        for (int i = 0; i < 32; ++i) t += part[i];
        partials[blockIdx.x] = t;            // plain store, deterministic
    }
}

// Single block: reduce nblk partials (all freshly written), write -log(sum).
__global__ __launch_bounds__(1024) void contrast_final(
    const float* __restrict__ partials, float* __restrict__ out, int nblk)
{
    float s = 0.0f;
    for (int i = threadIdx.x; i < nblk; i += 1024)
        s += partials[i];

    #pragma unroll
    for (int off = 32; off > 0; off >>= 1)
        s += __shfl_xor(s, off);             // one-time wave64 butterfly

    __shared__ float w[16];
    if ((threadIdx.x & 63) == 0) w[threadIdx.x >> 6] = s;
    __syncthreads();
    if (threadIdx.x == 0) {
        float t = 0.f;
        #pragma unroll
        for (int i = 0; i < 16; ++i) t += w[i];
        out[0] = -logf(t);
    }
}

extern "C" void kernel_launch(void* const* d_in, const int* in_sizes, int n_in,
                              void* d_out, int out_size, void* d_ws, size_t ws_size,
                              hipStream_t stream) {
    const float* xr = (const float*)d_in[0];
    const float* xp = (const float*)d_in[1];
    const float* xn = (const float*)d_in[2];
    float* out      = (float*)d_out;
    float* partials = (float*)d_ws;

    const int N = in_sizes[0] / 128;         // 100000

    const int nslots = (N + 1) / 2;          // 50000 row-pairs
    int nblk = (nslots + 31) / 32;           // 1563 one-shot blocks
    const int cap = (int)(ws_size / sizeof(float));
    if (nblk > cap) nblk = cap;              // safety: grid-stride covers rest

    contrast_partial<<<nblk, 256, 0, stream>>>(xr, xp, xn, partials, N);
    contrast_final<<<1, 1024, 0, stream>>>(partials, out, nblk);
}